// Round 2
// baseline (2886.892 us; speedup 1.0000x reference)
//
#include <hip/hip_runtime.h>
#include <hip/hip_bf16.h>
#include <hip/hip_fp16.h>

#define N_ATOM 100000
#define N_EDGE 1200000
#define N_CRYS 3125
#define EPSF 1e-5f

typedef __attribute__((ext_vector_type(8))) short bf16x8;
typedef __attribute__((ext_vector_type(4))) float f32x4;

__device__ __forceinline__ float softplusf(float x) {
    return fmaxf(x, 0.f) + log1pf(expf(-fabsf(x)));
}

// read element i of a float buffer whose dtype is f32 (isf32=1) or bf16 (0)
__device__ __forceinline__ float ldf(const void* p, long i, int isf32) {
    return isf32 ? ((const float*)p)[i]
                 : __bfloat162float(((const __hip_bfloat16*)p)[i]);
}

// ---------------- dtype detection ----------------
// atom_fea ~ N(0,1). As bf16: nearly all u16s have exponent field in [100,140].
// As f32: odd u16s (high halves) do, even u16s (low mantissa) are ~uniform.
__global__ void detect_dtype(const unsigned short* __restrict__ af,
                             int* __restrict__ flag) {
    __shared__ int cnt;
    if (threadIdx.x == 0) cnt = 0;
    __syncthreads();
    int c = 0;
    for (int i = threadIdx.x; i < 4096; i += 256) {
        int e = (af[i] >> 7) & 0xFF;
        if (e >= 100 && e <= 140) c++;
    }
    atomicAdd(&cnt, c);
    __syncthreads();
    if (threadIdx.x == 0) flag[0] = (cnt < 3300) ? 1 : 0;  // 1 = f32 inputs
}

// convert all small params to one f32 staging buffer
// layout: embW 0, embb 5888, bn1g 5952, bn1b 6336, bn2g 6720, bn2b 6912,
//         fc1W 7104, fc1b 15296, outW 15424, outb 15552  (total 15553)
__global__ void cvt_params(const void* embW, const void* embb, const void* bn1g,
                           const void* bn1b, const void* bn2g, const void* bn2b,
                           const void* fc1W, const void* fc1b, const void* outW,
                           const void* outb, const int* __restrict__ flag,
                           float* __restrict__ dst) {
    int f = flag[0];
    const void* ps[10] = {embW, embb, bn1g, bn1b, bn2g, bn2b, fc1W, fc1b, outW, outb};
    const int off[10]  = {0, 5888, 5952, 6336, 6720, 6912, 7104, 15296, 15424, 15552};
    const int n[10]    = {5888, 64, 384, 384, 192, 192, 8192, 128, 128, 1};
    for (int it = 0; it < 10; ++it)
        for (int i = threadIdx.x; i < n[it]; i += 256)
            dst[off[it] + i] = ldf(ps[it], i, f);
}

// ---------------- prep kernels ----------------

// nbr_fea (E x 41) -> nbr_pad (E x 64 bf16, zero padded)
__global__ void pad_nbr(const void* __restrict__ nf, const int* __restrict__ flag,
                        __hip_bfloat16* __restrict__ np_) {
    int f = flag[0];
    long i = (long)blockIdx.x * 256 + threadIdx.x;   // i < E*64
    long e = i >> 6;
    int  k = (int)(i & 63);
    float v = (k < 41) ? ldf(nf, e * 41 + k, f) : 0.f;
    np_[i] = __float2bfloat16(v);
}

// pack conv_W (3 x 169 x 128) into MFMA B-fragment order, K padded to 192.
// wf[layer][c][t][lane][j] = W[k=32c+8q+j][n=16t+m], q=lane>>4, m=lane&15
__global__ void pack_W(const void* __restrict__ convW, const int* __restrict__ flag,
                       __hip_bfloat16* __restrict__ wf) {
    int f = flag[0];
    int b = blockIdx.x;              // 3*6*8 = 144 blocks
    int l = threadIdx.x;             // 64 lanes
    int t = b & 7;
    int c = (b >> 3) % 6;
    int layer = b / 48;
    int q = l >> 4, m = l & 15;
    for (int j = 0; j < 8; ++j) {
        int k = 32 * c + 8 * q + j;
        int n = 16 * t + m;
        float v = (k < 169) ? ldf(convW, ((long)layer * 169 + k) * 128 + n, f) : 0.f;
        wf[((((long)layer * 6 + c) * 8 + t) * 64 + l) * 8 + j] = __float2bfloat16(v);
    }
}

// x = atom_fea @ emb_W + emb_b ; write f32 master + bf16 copy
__global__ void embed(const void* __restrict__ af, const float* __restrict__ pb,
                      const int* __restrict__ flag,
                      float* __restrict__ x, __hip_bfloat16* __restrict__ xb) {
    __shared__ float A[4][92];
    int f = flag[0];
    int a0 = blockIdx.x * 4;
    for (int i = threadIdx.x; i < 4 * 92; i += 256)
        A[i / 92][i % 92] = ldf(af, (long)a0 * 92 + i, f);
    __syncthreads();
    int al = threadIdx.x >> 6, cc = threadIdx.x & 63;
    long ga = a0 + al;
    float s = pb[5888 + cc];                       // emb_b
    for (int k = 0; k < 92; ++k)
        s += A[al][k] * pb[k * 64 + cc];           // emb_W
    x[ga * 64 + cc] = s;
    xb[ga * 64 + cc] = __float2bfloat16(s);
}

// rp[a] = lower_bound(idx[0:len], a), for a in [0, nseg]
__global__ void build_rowptr(const int* __restrict__ idx, int len, int nseg,
                             int* __restrict__ rp) {
    int a = blockIdx.x * 256 + threadIdx.x;
    if (a > nseg) return;
    int lo = 0, hi = len;
    while (lo < hi) {
        int mid = (lo + hi) >> 1;
        if (idx[mid] < a) lo = mid + 1; else hi = mid;
    }
    rp[a] = lo;
}

// ---------------- conv layer pass 1: gather + MFMA + stat partials ----------------
__global__ __launch_bounds__(256) void conv_mm(
    const __hip_bfloat16* __restrict__ xb,
    const __hip_bfloat16* __restrict__ nbrp,
    const __hip_bfloat16* __restrict__ wf,
    const int* __restrict__ self_idx,
    const int* __restrict__ nbr_idx,
    __half* __restrict__ y16,
    float* __restrict__ part1) {
    __shared__ float lstat[256];
    int tid = threadIdx.x;
    lstat[tid] = 0.f;
    __syncthreads();

    int wv = tid >> 6;
    int l  = tid & 63;
    int q  = l >> 4;
    int m  = l & 15;
    long eb = (long)blockIdx.x * 64 + wv * 16;
    long e  = eb + m;
    long self_base = (long)self_idx[e] * 64;
    long nbr_base  = (long)nbr_idx[e]  * 64;
    long edge_base = e * 64;
    const short* xs = (const short*)xb;
    const short* ns = (const short*)nbrp;
    const bf16x8* wfp = (const bf16x8*)wf;

    f32x4 acc[8];
#pragma unroll
    for (int t = 0; t < 8; ++t) acc[t] = (f32x4){0.f, 0.f, 0.f, 0.f};

#pragma unroll
    for (int c = 0; c < 6; ++c) {
        const short* src;
        long off;
        if (c < 2)      { src = xs; off = self_base + 32 * c       + 8 * q; }
        else if (c < 4) { src = xs; off = nbr_base  + 32 * (c - 2) + 8 * q; }
        else            { src = ns; off = edge_base + 32 * (c - 4) + 8 * q; }
        bf16x8 a = *(const bf16x8*)(src + off);
#pragma unroll
        for (int t = 0; t < 8; ++t) {
            bf16x8 b = wfp[(c * 8 + t) * 64 + l];
            acc[t] = __builtin_amdgcn_mfma_f32_16x16x32_bf16(a, b, acc[t], 0, 0, 0);
        }
    }

#pragma unroll
    for (int t = 0; t < 8; ++t) {
        float s = 0.f, sq = 0.f;
#pragma unroll
        for (int r = 0; r < 4; ++r) {
            float v = acc[t][r];
            long er = eb + q * 4 + r;           // C/D: row=(lane>>4)*4+r, col=lane&15
            y16[er * 128 + 16 * t + m] = __float2half(v);
            s += v; sq += v * v;
        }
        s  += __shfl_xor(s, 16, 64);  s  += __shfl_xor(s, 32, 64);
        sq += __shfl_xor(sq, 16, 64); sq += __shfl_xor(sq, 32, 64);
        if (q == 0) {
            atomicAdd(&lstat[16 * t + m], s);
            atomicAdd(&lstat[128 + 16 * t + m], sq);
        }
    }
    __syncthreads();
    part1[(long)blockIdx.x * 256 + tid] = lstat[tid];
}

// generic column-wise row-block reduction; blockDim.x = ncols
__global__ void reduce_rows(const float* __restrict__ src, float* __restrict__ dst,
                            int nrows, int rpb) {
    int ncols = blockDim.x;
    int col = threadIdx.x;
    long r0 = (long)blockIdx.x * rpb;
    long r1 = r0 + rpb; if (r1 > nrows) r1 = nrows;
    float s = 0.f;
    for (long r = r0; r < r1; ++r) s += src[r * ncols + col];
    dst[(long)blockIdx.x * ncols + col] = s;
}

// ---------------- conv layer pass 2: BN1 + gate + segment sum ----------------
__global__ __launch_bounds__(256) void conv_msg(
    const __half* __restrict__ y16,
    const int* __restrict__ rp,
    const float* __restrict__ stats1,     // [sum(128) | sumsq(128)]
    const float* __restrict__ g1,
    const float* __restrict__ b1,
    float* __restrict__ summed,
    float* __restrict__ part2,
    float invE) {
    __shared__ float lp[128];
    int tid = threadIdx.x;
    if (tid < 128) lp[tid] = 0.f;
    __syncthreads();
    int wv = tid >> 6, j = tid & 63;
    int a = blockIdx.x * 4 + wv;
    if (a < N_ATOM) {
        float mf = stats1[j] * invE;
        float vf = stats1[128 + j] * invE - mf * mf;
        float mc = stats1[64 + j] * invE;
        float vc = stats1[192 + j] * invE - mc * mc;
        float rf = rsqrtf(fmaxf(vf, 0.f) + EPSF) * g1[j];
        float rc = rsqrtf(fmaxf(vc, 0.f) + EPSF) * g1[64 + j];
        float bf = b1[j];
        float bc = b1[64 + j];
        int e0 = rp[a], e1 = rp[a + 1];
        float s = 0.f;
        for (int e = e0; e < e1; ++e) {
            float fv = __half2float(y16[(long)e * 128 + j]);
            float cv = __half2float(y16[(long)e * 128 + 64 + j]);
            fv = (fv - mf) * rf + bf;
            cv = (cv - mc) * rc + bc;
            float sg = 1.f / (1.f + expf(-fv));
            s += sg * softplusf(cv);
        }
        summed[(long)a * 64 + j] = s;
        atomicAdd(&lp[j], s);
        atomicAdd(&lp[64 + j], s * s);
    }
    __syncthreads();
    if (tid < 128) part2[(long)blockIdx.x * 128 + tid] = lp[tid];
}

// ---------------- conv layer pass 3: x = sp(x + bn2(summed)) ----------------
__global__ void update_x(float* __restrict__ x, __hip_bfloat16* __restrict__ xb,
                         const float* __restrict__ summed,
                         const float* __restrict__ stats2,   // [sum(64)|sumsq(64)]
                         const float* __restrict__ g2,
                         const float* __restrict__ b2,
                         float invN) {
    long i = (long)blockIdx.x * 256 + threadIdx.x;
    int j = (int)(i & 63);
    float m = stats2[j] * invN;
    float v = stats2[64 + j] * invN - m * m;
    float val = (summed[i] - m) * rsqrtf(fmaxf(v, 0.f) + EPSF) * g2[j] + b2[j];
    float sp = softplusf(x[i] + val);
    x[i] = sp;
    xb[i] = __float2bfloat16(sp);
}

// ---------------- pooling + head ----------------
__global__ void pool(const float* __restrict__ x, const int* __restrict__ cp,
                     float* __restrict__ crys_sp) {
    int wv = threadIdx.x >> 6, j = threadIdx.x & 63;
    int c = blockIdx.x * 4 + wv;
    if (c >= N_CRYS) return;
    int a0 = cp[c], a1 = cp[c + 1];
    float s = 0.f;
    for (int a = a0; a < a1; ++a) s += x[(long)a * 64 + j];
    float cnt = (float)(a1 - a0);
    float mean = s / fmaxf(cnt, 1.f);
    crys_sp[c * 64 + j] = softplusf(mean);
}

// block per crystal, 128 threads
__global__ void head(const float* __restrict__ crys_sp,
                     const float* __restrict__ pb,
                     const int* __restrict__ flag,
                     void* __restrict__ out) {
    __shared__ float row[64];
    __shared__ float hred[128];
    int c = blockIdx.x, t = threadIdx.x;
    if (t < 64) row[t] = crys_sp[c * 64 + t];
    __syncthreads();
    float d = pb[15296 + t];                          // fc1_b
    for (int k = 0; k < 64; ++k)
        d += row[k] * pb[7104 + k * 128 + t];         // fc1_W
    float h = softplusf(d);
    hred[t] = h * pb[15424 + t];                      // out_W
    __syncthreads();
    for (int off = 64; off > 0; off >>= 1) {
        if (t < off) hred[t] += hred[t + off];
        __syncthreads();
    }
    if (t == 0) {
        float v = hred[0] + pb[15552];                // out_b
        if (flag[0]) ((float*)out)[c] = v;
        else         ((__hip_bfloat16*)out)[c] = __float2bfloat16(v);
    }
}

// ---------------- launch ----------------
extern "C" void kernel_launch(void* const* d_in, const int* in_sizes, int n_in,
                              void* d_out, int out_size, void* d_ws, size_t ws_size,
                              hipStream_t stream) {
    const void* atom_fea = d_in[0];
    const void* nbr_fea  = d_in[1];
    const int* self_idx = (const int*)d_in[2];
    const int* nbr_idx  = (const int*)d_in[3];
    const int* crys_idx = (const int*)d_in[4];
    const void* emb_W  = d_in[5];
    const void* emb_b  = d_in[6];
    const void* conv_W = d_in[7];
    // d_in[8] = conv_b : cancels exactly inside BN1 -> unused
    const void* bn1_g  = d_in[9];
    const void* bn1_b  = d_in[10];
    const void* bn2_g  = d_in[11];
    const void* bn2_b  = d_in[12];
    const void* fc1_W  = d_in[13];
    const void* fc1_b  = d_in[14];
    const void* out_W  = d_in[15];
    const void* out_b  = d_in[16];

    char* ws = (char*)d_ws;
    size_t off = 0;
    auto alloc = [&](size_t b) {
        void* p = ws + off;
        off = (off + b + 255) & ~(size_t)255;
        return p;
    };
    float*          x      = (float*)alloc((size_t)N_ATOM * 64 * 4);
    __hip_bfloat16* xb     = (__hip_bfloat16*)alloc((size_t)N_ATOM * 64 * 2);
    __hip_bfloat16* nbrp   = (__hip_bfloat16*)alloc((size_t)N_EDGE * 64 * 2);
    __hip_bfloat16* wfr    = (__hip_bfloat16*)alloc((size_t)3 * 24576 * 2);
    __half*         y16    = (__half*)alloc((size_t)N_EDGE * 128 * 2);
    float*          part1  = (float*)alloc((size_t)18750 * 256 * 4);
    float*          red1   = (float*)alloc((size_t)147 * 256 * 4);
    float*          stats1 = (float*)alloc(256 * 4);
    float*          summed = (float*)alloc((size_t)N_ATOM * 64 * 4);
    float*          part2  = (float*)alloc((size_t)25000 * 128 * 4);
    float*          red2   = (float*)alloc((size_t)98 * 128 * 4);
    float*          stats2 = (float*)alloc(128 * 4);
    int*            rp     = (int*)alloc((N_ATOM + 1) * 4);
    int*            cp     = (int*)alloc((N_CRYS + 1) * 4);
    float*          crysp  = (float*)alloc((size_t)N_CRYS * 64 * 4);
    float*          pbuf   = (float*)alloc(15553 * 4);
    int*            dflag  = (int*)alloc(4);
    (void)ws_size; (void)in_sizes; (void)n_in; (void)out_size;

    detect_dtype<<<1, 256, 0, stream>>>((const unsigned short*)atom_fea, dflag);
    cvt_params<<<1, 256, 0, stream>>>(emb_W, emb_b, bn1_g, bn1_b, bn2_g, bn2_b,
                                      fc1_W, fc1_b, out_W, out_b, dflag, pbuf);
    pad_nbr<<<N_EDGE * 64 / 256, 256, 0, stream>>>(nbr_fea, dflag, nbrp);
    pack_W<<<144, 64, 0, stream>>>(conv_W, dflag, wfr);
    embed<<<N_ATOM / 4, 256, 0, stream>>>(atom_fea, pbuf, dflag, x, xb);
    build_rowptr<<<(N_ATOM + 1 + 255) / 256, 256, 0, stream>>>(self_idx, N_EDGE, N_ATOM, rp);
    build_rowptr<<<(N_CRYS + 1 + 255) / 256, 256, 0, stream>>>(crys_idx, N_ATOM, N_CRYS, cp);

    for (int l = 0; l < 3; ++l) {
        conv_mm<<<N_EDGE / 64, 256, 0, stream>>>(xb, nbrp, wfr + (size_t)l * 24576,
                                                 self_idx, nbr_idx, y16, part1);
        reduce_rows<<<147, 256, 0, stream>>>(part1, red1, 18750, 128);
        reduce_rows<<<1, 256, 0, stream>>>(red1, stats1, 147, 147);
        conv_msg<<<N_ATOM / 4, 256, 0, stream>>>(y16, rp, stats1,
                                                 pbuf + 5952 + (size_t)l * 128,
                                                 pbuf + 6336 + (size_t)l * 128,
                                                 summed, part2, 1.f / (float)N_EDGE);
        reduce_rows<<<98, 128, 0, stream>>>(part2, red2, 25000, 256);
        reduce_rows<<<1, 128, 0, stream>>>(red2, stats2, 98, 98);
        update_x<<<N_ATOM * 64 / 256, 256, 0, stream>>>(x, xb, summed, stats2,
                                                        pbuf + 6720 + (size_t)l * 64,
                                                        pbuf + 6912 + (size_t)l * 64,
                                                        1.f / (float)N_ATOM);
    }

    pool<<<(N_CRYS + 3) / 4, 256, 0, stream>>>(x, cp, crysp);
    head<<<N_CRYS, 128, 0, stream>>>(crysp, pbuf, dflag, (void*)d_out);
}

// Round 3
// 2407.886 us; speedup vs baseline: 1.1989x; 1.1989x over previous
//
#include <hip/hip_runtime.h>
#include <hip/hip_bf16.h>
#include <hip/hip_fp16.h>

#define N_ATOM 100000
#define N_EDGE 1200000
#define N_CRYS 3125
#define EPSF 1e-5f

typedef __attribute__((ext_vector_type(8))) short bf16x8;
typedef __attribute__((ext_vector_type(4))) float f32x4;

// ---- fast transcendentals (hardware v_exp_f32 / v_log_f32 / v_rcp_f32) ----
__device__ __forceinline__ float fexp(float x) {
    return __builtin_amdgcn_exp2f(x * 1.4426950408889634f);
}
__device__ __forceinline__ float flog(float x) {
    return __builtin_amdgcn_logf(x) * 0.6931471805599453f;
}
__device__ __forceinline__ float frcp(float x) { return __builtin_amdgcn_rcpf(x); }

__device__ __forceinline__ float softplusf(float x) {
    // max(x,0) + log1p(exp(-|x|)); arg of flog is in [1,2] -> full hw accuracy
    return fmaxf(x, 0.f) + flog(1.f + fexp(-fabsf(x)));
}
__device__ __forceinline__ float sigmoidf(float x) {
    return frcp(1.f + fexp(-x));
}

// read element i of a float buffer whose dtype is f32 (isf32=1) or bf16 (0)
__device__ __forceinline__ float ldf(const void* p, long i, int isf32) {
    return isf32 ? ((const float*)p)[i]
                 : __bfloat162float(((const __hip_bfloat16*)p)[i]);
}

// ---------------- dtype detection ----------------
__global__ void detect_dtype(const unsigned short* __restrict__ af,
                             int* __restrict__ flag) {
    __shared__ int cnt;
    if (threadIdx.x == 0) cnt = 0;
    __syncthreads();
    int c = 0;
    for (int i = threadIdx.x; i < 4096; i += 256) {
        int e = (af[i] >> 7) & 0xFF;
        if (e >= 100 && e <= 140) c++;
    }
    atomicAdd(&cnt, c);
    __syncthreads();
    if (threadIdx.x == 0) flag[0] = (cnt < 3300) ? 1 : 0;  // 1 = f32 inputs
}

// convert all small params to one f32 staging buffer
// layout: embW 0, embb 5888, bn1g 5952, bn1b 6336, bn2g 6720, bn2b 6912,
//         fc1W 7104, fc1b 15296, outW 15424, outb 15552  (total 15553)
__global__ void cvt_params(const void* embW, const void* embb, const void* bn1g,
                           const void* bn1b, const void* bn2g, const void* bn2b,
                           const void* fc1W, const void* fc1b, const void* outW,
                           const void* outb, const int* __restrict__ flag,
                           float* __restrict__ dst) {
    int f = flag[0];
    const void* ps[10] = {embW, embb, bn1g, bn1b, bn2g, bn2b, fc1W, fc1b, outW, outb};
    const int off[10]  = {0, 5888, 5952, 6336, 6720, 6912, 7104, 15296, 15424, 15552};
    const int n[10]    = {5888, 64, 384, 384, 192, 192, 8192, 128, 128, 1};
    for (int it = 0; it < 10; ++it)
        for (int i = threadIdx.x; i < n[it]; i += 256)
            dst[off[it] + i] = ldf(ps[it], i, f);
}

// ---------------- prep kernels ----------------

// nbr_fea (E x 41) -> nbr_pad (E x 64 bf16, zero padded)
__global__ void pad_nbr(const void* __restrict__ nf, const int* __restrict__ flag,
                        __hip_bfloat16* __restrict__ np_) {
    int f = flag[0];
    long i = (long)blockIdx.x * 256 + threadIdx.x;   // i < E*64
    long e = i >> 6;
    int  k = (int)(i & 63);
    float v = (k < 41) ? ldf(nf, e * 41 + k, f) : 0.f;
    np_[i] = __float2bfloat16(v);
}

// pack conv_W (3 x 169 x 128) into MFMA B-fragment order, K padded to 192.
// wf[layer][c][t][lane][j] = W[k=32c+8q+j][n=16t+m], q=lane>>4, m=lane&15
__global__ void pack_W(const void* __restrict__ convW, const int* __restrict__ flag,
                       __hip_bfloat16* __restrict__ wf) {
    int f = flag[0];
    int b = blockIdx.x;              // 3*6*8 = 144 blocks
    int l = threadIdx.x;             // 64 lanes
    int t = b & 7;
    int c = (b >> 3) % 6;
    int layer = b / 48;
    int q = l >> 4, m = l & 15;
    for (int j = 0; j < 8; ++j) {
        int k = 32 * c + 8 * q + j;
        int n = 16 * t + m;
        float v = (k < 169) ? ldf(convW, ((long)layer * 169 + k) * 128 + n, f) : 0.f;
        wf[((((long)layer * 6 + c) * 8 + t) * 64 + l) * 8 + j] = __float2bfloat16(v);
    }
}

// x = atom_fea @ emb_W + emb_b ; write f32 master + bf16 copy
__global__ void embed(const void* __restrict__ af, const float* __restrict__ pb,
                      const int* __restrict__ flag,
                      float* __restrict__ x, __hip_bfloat16* __restrict__ xb) {
    __shared__ float A[4][92];
    int f = flag[0];
    int a0 = blockIdx.x * 4;
    for (int i = threadIdx.x; i < 4 * 92; i += 256)
        A[i / 92][i % 92] = ldf(af, (long)a0 * 92 + i, f);
    __syncthreads();
    int al = threadIdx.x >> 6, cc = threadIdx.x & 63;
    long ga = a0 + al;
    float s = pb[5888 + cc];                       // emb_b
    for (int k = 0; k < 92; ++k)
        s += A[al][k] * pb[k * 64 + cc];           // emb_W
    x[ga * 64 + cc] = s;
    xb[ga * 64 + cc] = __float2bfloat16(s);
}

// rp[a] = lower_bound(idx[0:len], a), for a in [0, nseg]
__global__ void build_rowptr(const int* __restrict__ idx, int len, int nseg,
                             int* __restrict__ rp) {
    int a = blockIdx.x * 256 + threadIdx.x;
    if (a > nseg) return;
    int lo = 0, hi = len;
    while (lo < hi) {
        int mid = (lo + hi) >> 1;
        if (idx[mid] < a) lo = mid + 1; else hi = mid;
    }
    rp[a] = lo;
}

// ---------------- conv layer pass 1: gather + MFMA + stat partials ----------------
__global__ __launch_bounds__(256) void conv_mm(
    const __hip_bfloat16* __restrict__ xb,
    const __hip_bfloat16* __restrict__ nbrp,
    const __hip_bfloat16* __restrict__ wf,
    const int* __restrict__ self_idx,
    const int* __restrict__ nbr_idx,
    __half* __restrict__ y16,
    float* __restrict__ part1) {
    __shared__ float lstat[256];
    int tid = threadIdx.x;
    lstat[tid] = 0.f;
    __syncthreads();

    int wv = tid >> 6;
    int l  = tid & 63;
    int q  = l >> 4;
    int m  = l & 15;
    long eb = (long)blockIdx.x * 64 + wv * 16;
    long e  = eb + m;
    long self_base = (long)self_idx[e] * 64;
    long nbr_base  = (long)nbr_idx[e]  * 64;
    long edge_base = e * 64;
    const short* xs = (const short*)xb;
    const short* ns = (const short*)nbrp;
    const bf16x8* wfp = (const bf16x8*)wf;

    f32x4 acc[8];
#pragma unroll
    for (int t = 0; t < 8; ++t) acc[t] = (f32x4){0.f, 0.f, 0.f, 0.f};

#pragma unroll
    for (int c = 0; c < 6; ++c) {
        const short* src;
        long off;
        if (c < 2)      { src = xs; off = self_base + 32 * c       + 8 * q; }
        else if (c < 4) { src = xs; off = nbr_base  + 32 * (c - 2) + 8 * q; }
        else            { src = ns; off = edge_base + 32 * (c - 4) + 8 * q; }
        bf16x8 a = *(const bf16x8*)(src + off);
#pragma unroll
        for (int t = 0; t < 8; ++t) {
            bf16x8 b = wfp[(c * 8 + t) * 64 + l];
            acc[t] = __builtin_amdgcn_mfma_f32_16x16x32_bf16(a, b, acc[t], 0, 0, 0);
        }
    }

#pragma unroll
    for (int t = 0; t < 8; ++t) {
        float s = 0.f, sq = 0.f;
#pragma unroll
        for (int r = 0; r < 4; ++r) {
            float v = acc[t][r];
            long er = eb + q * 4 + r;           // C/D: row=(lane>>4)*4+r, col=lane&15
            y16[er * 128 + 16 * t + m] = __float2half(v);
            s += v; sq += v * v;
        }
        s  += __shfl_xor(s, 16, 64);  s  += __shfl_xor(s, 32, 64);
        sq += __shfl_xor(sq, 16, 64); sq += __shfl_xor(sq, 32, 64);
        if (q == 0) {
            atomicAdd(&lstat[16 * t + m], s);
            atomicAdd(&lstat[128 + 16 * t + m], sq);
        }
    }
    __syncthreads();
    part1[(long)blockIdx.x * 256 + tid] = lstat[tid];
}

// generic column-wise row-block reduction; blockDim.x = ncols
__global__ void reduce_rows(const float* __restrict__ src, float* __restrict__ dst,
                            int nrows, int rpb) {
    int ncols = blockDim.x;
    int col = threadIdx.x;
    long r0 = (long)blockIdx.x * rpb;
    long r1 = r0 + rpb; if (r1 > nrows) r1 = nrows;
    float s = 0.f;
    for (long r = r0; r < r1; ++r) s += src[r * ncols + col];
    dst[(long)blockIdx.x * ncols + col] = s;
}

// ---------------- conv layer pass 2: BN1 + gate + segment sum ----------------
__global__ __launch_bounds__(256) void conv_msg(
    const __half* __restrict__ y16,
    const int* __restrict__ rp,
    const float* __restrict__ stats1,     // [sum(128) | sumsq(128)]
    const float* __restrict__ g1,
    const float* __restrict__ b1,
    float* __restrict__ summed,
    float* __restrict__ part2,
    float invE) {
    __shared__ float lp[128];
    int tid = threadIdx.x;
    if (tid < 128) lp[tid] = 0.f;
    __syncthreads();
    int wv = tid >> 6, j = tid & 63;
    int a = blockIdx.x * 4 + wv;
    if (a < N_ATOM) {
        float mf = stats1[j] * invE;
        float vf = stats1[128 + j] * invE - mf * mf;
        float mc = stats1[64 + j] * invE;
        float vc = stats1[192 + j] * invE - mc * mc;
        float rf = rsqrtf(fmaxf(vf, 0.f) + EPSF) * g1[j];
        float rc = rsqrtf(fmaxf(vc, 0.f) + EPSF) * g1[64 + j];
        float bf = b1[j];
        float bc = b1[64 + j];
        int e0 = rp[a], e1 = rp[a + 1];
        float s = 0.f;
        for (int e = e0; e < e1; ++e) {
            float fv = __half2float(y16[(long)e * 128 + j]);
            float cv = __half2float(y16[(long)e * 128 + 64 + j]);
            fv = (fv - mf) * rf + bf;
            cv = (cv - mc) * rc + bc;
            s += sigmoidf(fv) * softplusf(cv);
        }
        summed[(long)a * 64 + j] = s;
        atomicAdd(&lp[j], s);
        atomicAdd(&lp[64 + j], s * s);
    }
    __syncthreads();
    if (tid < 128) part2[(long)blockIdx.x * 128 + tid] = lp[tid];
}

// ---------------- conv layer pass 3: x = sp(x + bn2(summed)) ----------------
__global__ void update_x(float* __restrict__ x, __hip_bfloat16* __restrict__ xb,
                         const float* __restrict__ summed,
                         const float* __restrict__ stats2,   // [sum(64)|sumsq(64)]
                         const float* __restrict__ g2,
                         const float* __restrict__ b2,
                         float invN) {
    long i = (long)blockIdx.x * 256 + threadIdx.x;
    int j = (int)(i & 63);
    float m = stats2[j] * invN;
    float v = stats2[64 + j] * invN - m * m;
    float val = (summed[i] - m) * rsqrtf(fmaxf(v, 0.f) + EPSF) * g2[j] + b2[j];
    float sp = softplusf(x[i] + val);
    x[i] = sp;
    xb[i] = __float2bfloat16(sp);
}

// ---------------- pooling + head ----------------
__global__ void pool(const float* __restrict__ x, const int* __restrict__ cp,
                     float* __restrict__ crys_sp) {
    int wv = threadIdx.x >> 6, j = threadIdx.x & 63;
    int c = blockIdx.x * 4 + wv;
    if (c >= N_CRYS) return;
    int a0 = cp[c], a1 = cp[c + 1];
    float s = 0.f;
    for (int a = a0; a < a1; ++a) s += x[(long)a * 64 + j];
    float cnt = (float)(a1 - a0);
    float mean = s / fmaxf(cnt, 1.f);
    crys_sp[c * 64 + j] = softplusf(mean);
}

// block per crystal, 128 threads
__global__ void head(const float* __restrict__ crys_sp,
                     const float* __restrict__ pb,
                     const int* __restrict__ flag,
                     void* __restrict__ out) {
    __shared__ float row[64];
    __shared__ float hred[128];
    int c = blockIdx.x, t = threadIdx.x;
    if (t < 64) row[t] = crys_sp[c * 64 + t];
    __syncthreads();
    float d = pb[15296 + t];                          // fc1_b
    for (int k = 0; k < 64; ++k)
        d += row[k] * pb[7104 + k * 128 + t];         // fc1_W
    float h = softplusf(d);
    hred[t] = h * pb[15424 + t];                      // out_W
    __syncthreads();
    for (int off = 64; off > 0; off >>= 1) {
        if (t < off) hred[t] += hred[t + off];
        __syncthreads();
    }
    if (t == 0) {
        float v = hred[0] + pb[15552];                // out_b
        if (flag[0]) ((float*)out)[c] = v;
        else         ((__hip_bfloat16*)out)[c] = __float2bfloat16(v);
    }
}

// ---------------- launch ----------------
extern "C" void kernel_launch(void* const* d_in, const int* in_sizes, int n_in,
                              void* d_out, int out_size, void* d_ws, size_t ws_size,
                              hipStream_t stream) {
    const void* atom_fea = d_in[0];
    const void* nbr_fea  = d_in[1];
    const int* self_idx = (const int*)d_in[2];
    const int* nbr_idx  = (const int*)d_in[3];
    const int* crys_idx = (const int*)d_in[4];
    const void* emb_W  = d_in[5];
    const void* emb_b  = d_in[6];
    const void* conv_W = d_in[7];
    // d_in[8] = conv_b : cancels exactly inside BN1 -> unused
    const void* bn1_g  = d_in[9];
    const void* bn1_b  = d_in[10];
    const void* bn2_g  = d_in[11];
    const void* bn2_b  = d_in[12];
    const void* fc1_W  = d_in[13];
    const void* fc1_b  = d_in[14];
    const void* out_W  = d_in[15];
    const void* out_b  = d_in[16];

    char* ws = (char*)d_ws;
    size_t off = 0;
    auto alloc = [&](size_t b) {
        void* p = ws + off;
        off = (off + b + 255) & ~(size_t)255;
        return p;
    };
    float*          x      = (float*)alloc((size_t)N_ATOM * 64 * 4);
    __hip_bfloat16* xb     = (__hip_bfloat16*)alloc((size_t)N_ATOM * 64 * 2);
    __hip_bfloat16* nbrp   = (__hip_bfloat16*)alloc((size_t)N_EDGE * 64 * 2);
    __hip_bfloat16* wfr    = (__hip_bfloat16*)alloc((size_t)3 * 24576 * 2);
    __half*         y16    = (__half*)alloc((size_t)N_EDGE * 128 * 2);
    float*          part1  = (float*)alloc((size_t)18750 * 256 * 4);
    float*          red1   = (float*)alloc((size_t)147 * 256 * 4);
    float*          stats1 = (float*)alloc(256 * 4);
    float*          summed = (float*)alloc((size_t)N_ATOM * 64 * 4);
    float*          part2  = (float*)alloc((size_t)25000 * 128 * 4);
    float*          red2   = (float*)alloc((size_t)98 * 128 * 4);
    float*          stats2 = (float*)alloc(128 * 4);
    int*            rp     = (int*)alloc((N_ATOM + 1) * 4);
    int*            cp     = (int*)alloc((N_CRYS + 1) * 4);
    float*          crysp  = (float*)alloc((size_t)N_CRYS * 64 * 4);
    float*          pbuf   = (float*)alloc(15553 * 4);
    int*            dflag  = (int*)alloc(4);
    (void)ws_size; (void)in_sizes; (void)n_in; (void)out_size;

    detect_dtype<<<1, 256, 0, stream>>>((const unsigned short*)atom_fea, dflag);
    cvt_params<<<1, 256, 0, stream>>>(emb_W, emb_b, bn1_g, bn1_b, bn2_g, bn2_b,
                                      fc1_W, fc1_b, out_W, out_b, dflag, pbuf);
    pad_nbr<<<N_EDGE * 64 / 256, 256, 0, stream>>>(nbr_fea, dflag, nbrp);
    pack_W<<<144, 64, 0, stream>>>(conv_W, dflag, wfr);
    embed<<<N_ATOM / 4, 256, 0, stream>>>(atom_fea, pbuf, dflag, x, xb);
    build_rowptr<<<(N_ATOM + 1 + 255) / 256, 256, 0, stream>>>(self_idx, N_EDGE, N_ATOM, rp);
    build_rowptr<<<(N_CRYS + 1 + 255) / 256, 256, 0, stream>>>(crys_idx, N_ATOM, N_CRYS, cp);

    for (int l = 0; l < 3; ++l) {
        conv_mm<<<N_EDGE / 64, 256, 0, stream>>>(xb, nbrp, wfr + (size_t)l * 24576,
                                                 self_idx, nbr_idx, y16, part1);
        reduce_rows<<<147, 256, 0, stream>>>(part1, red1, 18750, 128);
        reduce_rows<<<1, 256, 0, stream>>>(red1, stats1, 147, 147);
        conv_msg<<<N_ATOM / 4, 256, 0, stream>>>(y16, rp, stats1,
                                                 pbuf + 5952 + (size_t)l * 128,
                                                 pbuf + 6336 + (size_t)l * 128,
                                                 summed, part2, 1.f / (float)N_EDGE);
        reduce_rows<<<98, 128, 0, stream>>>(part2, red2, 25000, 256);
        reduce_rows<<<1, 128, 0, stream>>>(red2, stats2, 98, 98);
        update_x<<<N_ATOM * 64 / 256, 256, 0, stream>>>(x, xb, summed, stats2,
                                                        pbuf + 6720 + (size_t)l * 64,
                                                        pbuf + 6912 + (size_t)l * 64,
                                                        1.f / (float)N_ATOM);
    }

    pool<<<(N_CRYS + 3) / 4, 256, 0, stream>>>(x, cp, crysp);
    head<<<N_CRYS, 128, 0, stream>>>(crysp, pbuf, dflag, (void*)d_out);
}

// Round 5
// 2154.094 us; speedup vs baseline: 1.3402x; 1.1178x over previous
//
#include <hip/hip_runtime.h>
#include <hip/hip_bf16.h>
#include <hip/hip_fp16.h>

#define N_ATOM 100000
#define N_EDGE 1200000
#define N_CRYS 3125
#define EPSF 1e-5f

typedef __attribute__((ext_vector_type(8))) short bf16x8;
typedef __attribute__((ext_vector_type(4))) float f32x4;

// ---- fast transcendentals (hardware v_exp_f32 / v_log_f32 / v_rcp_f32) ----
__device__ __forceinline__ float fexp(float x) {
    return __builtin_amdgcn_exp2f(x * 1.4426950408889634f);
}
__device__ __forceinline__ float flog(float x) {
    return __builtin_amdgcn_logf(x) * 0.6931471805599453f;
}
__device__ __forceinline__ float frcp(float x) { return __builtin_amdgcn_rcpf(x); }

__device__ __forceinline__ float softplusf(float x) {
    return fmaxf(x, 0.f) + flog(1.f + fexp(-fabsf(x)));
}
__device__ __forceinline__ float sigmoidf(float x) {
    return frcp(1.f + fexp(-x));
}

// read element i of a float buffer whose dtype is f32 (isf32=1) or bf16 (0)
__device__ __forceinline__ float ldf(const void* p, long i, int isf32) {
    return isf32 ? ((const float*)p)[i]
                 : __bfloat162float(((const __hip_bfloat16*)p)[i]);
}

// ---------------- dtype detection ----------------
__global__ void detect_dtype(const unsigned short* __restrict__ af,
                             int* __restrict__ flag) {
    __shared__ int cnt;
    if (threadIdx.x == 0) cnt = 0;
    __syncthreads();
    int c = 0;
    for (int i = threadIdx.x; i < 4096; i += 256) {
        int e = (af[i] >> 7) & 0xFF;
        if (e >= 100 && e <= 140) c++;
    }
    atomicAdd(&cnt, c);
    __syncthreads();
    if (threadIdx.x == 0) flag[0] = (cnt < 3300) ? 1 : 0;  // 1 = f32 inputs
}

// convert all small params to one f32 staging buffer
// layout: embW 0, embb 5888, bn1g 5952, bn1b 6336, bn2g 6720, bn2b 6912,
//         fc1W 7104, fc1b 15296, outW 15424, outb 15552  (total 15553)
__global__ void cvt_params(const void* embW, const void* embb, const void* bn1g,
                           const void* bn1b, const void* bn2g, const void* bn2b,
                           const void* fc1W, const void* fc1b, const void* outW,
                           const void* outb, const int* __restrict__ flag,
                           float* __restrict__ dst) {
    int f = flag[0];
    const void* ps[10] = {embW, embb, bn1g, bn1b, bn2g, bn2b, fc1W, fc1b, outW, outb};
    const int off[10]  = {0, 5888, 5952, 6336, 6720, 6912, 7104, 15296, 15424, 15552};
    const int n[10]    = {5888, 64, 384, 384, 192, 192, 8192, 128, 128, 1};
    for (int it = 0; it < 10; ++it)
        for (int i = threadIdx.x; i < n[it]; i += 256)
            dst[off[it] + i] = ldf(ps[it], i, f);
}

// ---------------- prep kernels ----------------

// nbr_fea (E x 41) -> nbr_pad (E x 64 bf16, zero padded)
__global__ void pad_nbr(const void* __restrict__ nf, const int* __restrict__ flag,
                        __hip_bfloat16* __restrict__ np_) {
    int f = flag[0];
    long i = (long)blockIdx.x * 256 + threadIdx.x;   // i < E*64
    long e = i >> 6;
    int  k = (int)(i & 63);
    float v = (k < 41) ? ldf(nf, e * 41 + k, f) : 0.f;
    np_[i] = __float2bfloat16(v);
}

// pack conv_W (3 x 169 x 128) into MFMA B-fragment order, K padded to 192.
// wf[layer][c][t][lane][j] = W[k=32c+8q+j][n=16t+m], q=lane>>4, m=lane&15
// (verified end-to-end in rounds 2-3)
__global__ void pack_W(const void* __restrict__ convW, const int* __restrict__ flag,
                       __hip_bfloat16* __restrict__ wf) {
    int f = flag[0];
    int b = blockIdx.x;              // 3*6*8 = 144 blocks
    int l = threadIdx.x;             // 64 lanes
    int t = b & 7;
    int c = (b >> 3) % 6;
    int layer = b / 48;
    int q = l >> 4, m = l & 15;
    for (int j = 0; j < 8; ++j) {
        int k = 32 * c + 8 * q + j;
        int n = 16 * t + m;
        float v = (k < 169) ? ldf(convW, ((long)layer * 169 + k) * 128 + n, f) : 0.f;
        wf[((((long)layer * 6 + c) * 8 + t) * 64 + l) * 8 + j] = __float2bfloat16(v);
    }
}

// x = atom_fea @ emb_W + emb_b ; write f32 master + bf16 copy
__global__ void embed(const void* __restrict__ af, const float* __restrict__ pb,
                      const int* __restrict__ flag,
                      float* __restrict__ x, __hip_bfloat16* __restrict__ xb) {
    __shared__ float A[4][92];
    int f = flag[0];
    int a0 = blockIdx.x * 4;
    for (int i = threadIdx.x; i < 4 * 92; i += 256)
        A[i / 92][i % 92] = ldf(af, (long)a0 * 92 + i, f);
    __syncthreads();
    int al = threadIdx.x >> 6, cc = threadIdx.x & 63;
    long ga = a0 + al;
    float s = pb[5888 + cc];                       // emb_b
    for (int k = 0; k < 92; ++k)
        s += A[al][k] * pb[k * 64 + cc];           // emb_W
    x[ga * 64 + cc] = s;
    xb[ga * 64 + cc] = __float2bfloat16(s);
}

// rp[a] = lower_bound(idx[0:len], a), for a in [0, nseg]
__global__ void build_rowptr(const int* __restrict__ idx, int len, int nseg,
                             int* __restrict__ rp) {
    int a = blockIdx.x * 256 + threadIdx.x;
    if (a > nseg) return;
    int lo = 0, hi = len;
    while (lo < hi) {
        int mid = (lo + hi) >> 1;
        if (idx[mid] < a) lo = mid + 1; else hi = mid;
    }
    rp[a] = lo;
}

// ---------------- conv layer pass 1: gather + MFMA(16x16x32), W in LDS ----------------
// 256 thr = 4 waves; each wave: 2 edge-tiles of 16 => 32 edges x 128 cols; block = 128 edges
__global__ __launch_bounds__(256, 4) void conv_mm16(
    const __hip_bfloat16* __restrict__ xb,
    const __hip_bfloat16* __restrict__ nbrp,
    const __hip_bfloat16* __restrict__ wf,      // this layer: 6*8*64*8 bf16 = 24576
    const int* __restrict__ self_idx,
    const int* __restrict__ nbr_idx,
    __half* __restrict__ y16,
    float* __restrict__ part1) {
    __shared__ __align__(16) __hip_bfloat16 wlds[24576];   // 48 KB
    __shared__ float lstat[256];
    int tid = threadIdx.x;
    {   // stage W fragments into LDS (3072 float4)
        const float4* wsrc = (const float4*)wf;
        float4* wdst = (float4*)wlds;
        for (int i = tid; i < 3072; i += 256) wdst[i] = wsrc[i];
    }
    lstat[tid] = 0.f;
    __syncthreads();

    int wv = tid >> 6;
    int l  = tid & 63;
    int q  = l >> 4;
    int m  = l & 15;
    long eb = (long)blockIdx.x * 128 + wv * 32;
    long sbase[2], nbase[2], ebase[2];
#pragma unroll
    for (int et = 0; et < 2; ++et) {
        long e = eb + 16 * et + m;
        sbase[et] = (long)self_idx[e] * 64;
        nbase[et] = (long)nbr_idx[e]  * 64;
        ebase[et] = e * 64;
    }
    const short* xs = (const short*)xb;
    const short* ns = (const short*)nbrp;
    const bf16x8* wl = (const bf16x8*)wlds;

    f32x4 acc[2][8];
#pragma unroll
    for (int et = 0; et < 2; ++et)
#pragma unroll
        for (int t = 0; t < 8; ++t) acc[et][t] = (f32x4){0.f, 0.f, 0.f, 0.f};

#pragma unroll
    for (int c = 0; c < 6; ++c) {
        bf16x8 a[2];
#pragma unroll
        for (int et = 0; et < 2; ++et) {
            const short* src;
            long off;
            if (c < 2)      { src = xs; off = sbase[et] + 32 * c       + 8 * q; }
            else if (c < 4) { src = xs; off = nbase[et] + 32 * (c - 2) + 8 * q; }
            else            { src = ns; off = ebase[et] + 32 * (c - 4) + 8 * q; }
            a[et] = *(const bf16x8*)(src + off);
        }
#pragma unroll
        for (int t = 0; t < 8; ++t) {
            bf16x8 b = wl[(c * 8 + t) * 64 + l];     // ds_read_b128
            acc[0][t] = __builtin_amdgcn_mfma_f32_16x16x32_bf16(a[0], b, acc[0][t], 0, 0, 0);
            acc[1][t] = __builtin_amdgcn_mfma_f32_16x16x32_bf16(a[1], b, acc[1][t], 0, 0, 0);
        }
    }

    // epilogue: y16 store + column sum/sumsq. C/D: row=(lane>>4)*4+r, col=lane&15
#pragma unroll
    for (int t = 0; t < 8; ++t) {
        float s = 0.f, sq = 0.f;
#pragma unroll
        for (int et = 0; et < 2; ++et) {
#pragma unroll
            for (int r = 0; r < 4; ++r) {
                float v = acc[et][t][r];
                long er = eb + 16 * et + q * 4 + r;
                y16[er * 128 + 16 * t + m] = __float2half(v);
                s += v; sq += v * v;
            }
        }
        s  += __shfl_xor(s, 16, 64);  s  += __shfl_xor(s, 32, 64);
        sq += __shfl_xor(sq, 16, 64); sq += __shfl_xor(sq, 32, 64);
        if (q == 0) {
            atomicAdd(&lstat[16 * t + m], s);
            atomicAdd(&lstat[128 + 16 * t + m], sq);
        }
    }
    __syncthreads();
    part1[(long)blockIdx.x * 256 + tid] = lstat[tid];
}

// generic column-wise row-block reduction; blockDim.x = ncols
__global__ void reduce_rows(const float* __restrict__ src, float* __restrict__ dst,
                            int nrows, int rpb) {
    int ncols = blockDim.x;
    int col = threadIdx.x;
    long r0 = (long)blockIdx.x * rpb;
    long r1 = r0 + rpb; if (r1 > nrows) r1 = nrows;
    float s = 0.f;
    for (long r = r0; r < r1; ++r) s += src[r * ncols + col];
    dst[(long)blockIdx.x * ncols + col] = s;
}

// ---------------- conv layer pass 2: BN1 + gate + segment sum ----------------
__global__ __launch_bounds__(256) void conv_msg(
    const __half* __restrict__ y16,
    const int* __restrict__ rp,
    const float* __restrict__ stats1,     // [sum(128) | sumsq(128)]
    const float* __restrict__ g1,
    const float* __restrict__ b1,
    float* __restrict__ summed,
    float* __restrict__ part2,
    float invE) {
    __shared__ float lp[128];
    int tid = threadIdx.x;
    if (tid < 128) lp[tid] = 0.f;
    __syncthreads();
    int wv = tid >> 6, j = tid & 63;
    int a = blockIdx.x * 4 + wv;
    if (a < N_ATOM) {
        float mf = stats1[j] * invE;
        float vf = stats1[128 + j] * invE - mf * mf;
        float mc = stats1[64 + j] * invE;
        float vc = stats1[192 + j] * invE - mc * mc;
        float rf = rsqrtf(fmaxf(vf, 0.f) + EPSF) * g1[j];
        float rc = rsqrtf(fmaxf(vc, 0.f) + EPSF) * g1[64 + j];
        float bf = b1[j];
        float bc = b1[64 + j];
        int e0 = rp[a], e1 = rp[a + 1];
        float s = 0.f;
        for (int e = e0; e < e1; ++e) {
            float fv = __half2float(y16[(long)e * 128 + j]);
            float cv = __half2float(y16[(long)e * 128 + 64 + j]);
            fv = (fv - mf) * rf + bf;
            cv = (cv - mc) * rc + bc;
            s += sigmoidf(fv) * softplusf(cv);
        }
        summed[(long)a * 64 + j] = s;
        atomicAdd(&lp[j], s);
        atomicAdd(&lp[64 + j], s * s);
    }
    __syncthreads();
    if (tid < 128) part2[(long)blockIdx.x * 128 + tid] = lp[tid];
}

// ---------------- conv layer pass 3: x = sp(x + bn2(summed)) ----------------
__global__ void update_x(float* __restrict__ x, __hip_bfloat16* __restrict__ xb,
                         const float* __restrict__ summed,
                         const float* __restrict__ stats2,   // [sum(64)|sumsq(64)]
                         const float* __restrict__ g2,
                         const float* __restrict__ b2,
                         float invN) {
    long i = (long)blockIdx.x * 256 + threadIdx.x;
    int j = (int)(i & 63);
    float m = stats2[j] * invN;
    float v = stats2[64 + j] * invN - m * m;
    float val = (summed[i] - m) * rsqrtf(fmaxf(v, 0.f) + EPSF) * g2[j] + b2[j];
    float sp = softplusf(x[i] + val);
    x[i] = sp;
    xb[i] = __float2bfloat16(sp);
}

// ---------------- pooling + head ----------------
__global__ void pool(const float* __restrict__ x, const int* __restrict__ cp,
                     float* __restrict__ crys_sp) {
    int wv = threadIdx.x >> 6, j = threadIdx.x & 63;
    int c = blockIdx.x * 4 + wv;
    if (c >= N_CRYS) return;
    int a0 = cp[c], a1 = cp[c + 1];
    float s = 0.f;
    for (int a = a0; a < a1; ++a) s += x[(long)a * 64 + j];
    float cnt = (float)(a1 - a0);
    float mean = s / fmaxf(cnt, 1.f);
    crys_sp[c * 64 + j] = softplusf(mean);
}

// block per crystal, 128 threads
__global__ void head(const float* __restrict__ crys_sp,
                     const float* __restrict__ pb,
                     const int* __restrict__ flag,
                     void* __restrict__ out) {
    __shared__ float row[64];
    __shared__ float hred[128];
    int c = blockIdx.x, t = threadIdx.x;
    if (t < 64) row[t] = crys_sp[c * 64 + t];
    __syncthreads();
    float d = pb[15296 + t];                          // fc1_b
    for (int k = 0; k < 64; ++k)
        d += row[k] * pb[7104 + k * 128 + t];         // fc1_W
    float h = softplusf(d);
    hred[t] = h * pb[15424 + t];                      // out_W
    __syncthreads();
    for (int off = 64; off > 0; off >>= 1) {
        if (t < off) hred[t] += hred[t + off];
        __syncthreads();
    }
    if (t == 0) {
        float v = hred[0] + pb[15552];                // out_b
        if (flag[0]) ((float*)out)[c] = v;
        else         ((__hip_bfloat16*)out)[c] = __float2bfloat16(v);
    }
}

// ---------------- launch ----------------
extern "C" void kernel_launch(void* const* d_in, const int* in_sizes, int n_in,
                              void* d_out, int out_size, void* d_ws, size_t ws_size,
                              hipStream_t stream) {
    const void* atom_fea = d_in[0];
    const void* nbr_fea  = d_in[1];
    const int* self_idx = (const int*)d_in[2];
    const int* nbr_idx  = (const int*)d_in[3];
    const int* crys_idx = (const int*)d_in[4];
    const void* emb_W  = d_in[5];
    const void* emb_b  = d_in[6];
    const void* conv_W = d_in[7];
    // d_in[8] = conv_b : cancels exactly inside BN1 -> unused
    const void* bn1_g  = d_in[9];
    const void* bn1_b  = d_in[10];
    const void* bn2_g  = d_in[11];
    const void* bn2_b  = d_in[12];
    const void* fc1_W  = d_in[13];
    const void* fc1_b  = d_in[14];
    const void* out_W  = d_in[15];
    const void* out_b  = d_in[16];

    char* ws = (char*)d_ws;
    size_t off = 0;
    auto alloc = [&](size_t b) {
        void* p = ws + off;
        off = (off + b + 255) & ~(size_t)255;
        return p;
    };
    float*          x      = (float*)alloc((size_t)N_ATOM * 64 * 4);
    __hip_bfloat16* xb     = (__hip_bfloat16*)alloc((size_t)N_ATOM * 64 * 2);
    __hip_bfloat16* nbrp   = (__hip_bfloat16*)alloc((size_t)N_EDGE * 64 * 2);
    __hip_bfloat16* wfr    = (__hip_bfloat16*)alloc((size_t)3 * 24576 * 2);
    __half*         y16    = (__half*)alloc((size_t)N_EDGE * 128 * 2);
    float*          part1  = (float*)alloc((size_t)9375 * 256 * 4);
    float*          red1   = (float*)alloc((size_t)74 * 256 * 4);
    float*          stats1 = (float*)alloc(256 * 4);
    float*          summed = (float*)alloc((size_t)N_ATOM * 64 * 4);
    float*          part2  = (float*)alloc((size_t)25000 * 128 * 4);
    float*          red2   = (float*)alloc((size_t)98 * 128 * 4);
    float*          stats2 = (float*)alloc(128 * 4);
    int*            rp     = (int*)alloc((N_ATOM + 1) * 4);
    int*            cp     = (int*)alloc((N_CRYS + 1) * 4);
    float*          crysp  = (float*)alloc((size_t)N_CRYS * 64 * 4);
    float*          pbuf   = (float*)alloc(15553 * 4);
    int*            dflag  = (int*)alloc(4);
    (void)ws_size; (void)in_sizes; (void)n_in; (void)out_size;

    detect_dtype<<<1, 256, 0, stream>>>((const unsigned short*)atom_fea, dflag);
    cvt_params<<<1, 256, 0, stream>>>(emb_W, emb_b, bn1_g, bn1_b, bn2_g, bn2_b,
                                      fc1_W, fc1_b, out_W, out_b, dflag, pbuf);
    pad_nbr<<<(int)((size_t)N_EDGE * 64 / 256), 256, 0, stream>>>(nbr_fea, dflag, nbrp);
    pack_W<<<144, 64, 0, stream>>>(conv_W, dflag, wfr);
    embed<<<N_ATOM / 4, 256, 0, stream>>>(atom_fea, pbuf, dflag, x, xb);
    build_rowptr<<<(N_ATOM + 1 + 255) / 256, 256, 0, stream>>>(self_idx, N_EDGE, N_ATOM, rp);
    build_rowptr<<<(N_CRYS + 1 + 255) / 256, 256, 0, stream>>>(crys_idx, N_ATOM, N_CRYS, cp);

    for (int l = 0; l < 3; ++l) {
        conv_mm16<<<9375, 256, 0, stream>>>(xb, nbrp, wfr + (size_t)l * 24576,
                                            self_idx, nbr_idx, y16, part1);
        reduce_rows<<<74, 256, 0, stream>>>(part1, red1, 9375, 127);
        reduce_rows<<<1, 256, 0, stream>>>(red1, stats1, 74, 74);
        conv_msg<<<N_ATOM / 4, 256, 0, stream>>>(y16, rp, stats1,
                                                 pbuf + 5952 + (size_t)l * 128,
                                                 pbuf + 6336 + (size_t)l * 128,
                                                 summed, part2, 1.f / (float)N_EDGE);
        reduce_rows<<<98, 128, 0, stream>>>(part2, red2, 25000, 256);
        reduce_rows<<<1, 128, 0, stream>>>(red2, stats2, 98, 98);
        update_x<<<N_ATOM * 64 / 256, 256, 0, stream>>>(x, xb, summed, stats2,
                                                        pbuf + 6720 + (size_t)l * 64,
                                                        pbuf + 6912 + (size_t)l * 64,
                                                        1.f / (float)N_ATOM);
    }

    pool<<<(N_CRYS + 3) / 4, 256, 0, stream>>>(x, cp, crysp);
    head<<<N_CRYS, 128, 0, stream>>>(crysp, pbuf, dflag, (void*)d_out);
}